// Round 2
// baseline (8202.032 us; speedup 1.0000x reference)
//
#include <hip/hip_runtime.h>
#include <hip/hip_bf16.h>

// LSTM + Gaussian attention (Graves), B=64, T=512, H=512, K=10, NC=80, U=64.
// 64 persistent blocks x 256 threads, each block owns 8 h-cols (32 gate cols).
// Wave w of each block owns batches [16w,16w+16) for ALL intra-step phases.
// R7 sync: FLAG-FREE tagged broadcast. Each lane publishes {2x bf16 h, u32 tag}
// as one atomic 8B store (sc-coherent via volatile). Consumers poll their own
// data granules; tag==t validates the data in the same load. No producer
// drain, no flags, no wave0 proxy poll, no __syncthreads in the loop.
// Grid decomposes into 4 independent rings (wave w of block i <-> wave w of
// block j); x_t staging is per-wave double-buffered.

#define GRID_BLOCKS 64
#define TPB 256

typedef __attribute__((ext_vector_type(8))) __bf16 bf16x8;
typedef __attribute__((ext_vector_type(4))) float f32x4;
typedef __attribute__((ext_vector_type(2))) float f32x2;
typedef __attribute__((ext_vector_type(4))) int i32x4;

struct Smem {
    alignas(16) __bf16 wBf[64 * 104];  // w (attention) bf16, padded stride 104
    float P[64 * 33];                  // window pre-acts (30 cols), stride 33
    float Gt[64 * 33];                 // gates scatter (32 cols), stride 33
    float Al[640];
    float Be[640];
    float Ka[640];                     // kappa (replicated per block)
    float Wacc[64 * 80];               // w accumulator fp32
    float Xt[2 * 192];                 // x_t staged, per-wave slices [buf][wave][48]
    float Maskv[4096];
    float Wx[96];                      // x-part weights, 32 cols x 3
    float Bsum[32];
    float Bwin[32];
    int   Act[64];
    unsigned char Sent[4096];
};

__device__ __forceinline__ float sigf(float x) {
    return 1.f / (1.f + __expf(-x));
}
__device__ __forceinline__ float tanh_fast(float x) {
    float xx = fminf(fmaxf(x, -15.f), 15.f);
    float e = __expf(2.f * xx);
    return (e - 1.f) / (e + 1.f);
}

__global__ void init_ws_kernel(int* ws) {
    // zero tagged h double-buffer: 2 x 64 batches x 256 granules x 8B = 256KB
    int idx = blockIdx.x * TPB + threadIdx.x;
    if (idx < 65536) ws[idx] = 0;
}

__global__ void __launch_bounds__(TPB, 1) lstm_attn(
    const float* __restrict__ strokes,    // [64][512][3]
    const int*   __restrict__ sentences,  // [64][64]
    const float* __restrict__ smask,      // [64][64]
    const float* __restrict__ Wih,        // [2048][83]
    const float* __restrict__ Whh,        // [2048][512]
    const float* __restrict__ bih,        // [2048]
    const float* __restrict__ bhh,        // [2048]
    const float* __restrict__ Wwin,      // [30][512]
    const float* __restrict__ bwin,      // [30]
    float* __restrict__ out,             // hs [64][512][512] ++ ws [64][512][80]
    unsigned long long* __restrict__ hbuf) // [2][64][256] granules {2xbf16, u32 tag}
{
    __shared__ Smem S;
    const int tid  = threadIdx.x;
    const int blk  = blockIdx.x;
    const int lane = tid & 63;
    const int wave = tid >> 6;
    const int lm   = lane & 15;   // MFMA n-col within tile / A row
    const int quad = lane >> 4;   // MFMA k-block
    const int myb  = wave * 16 + lm;
    const int koff = quad * 8;

    // ---------------- one-time init: B-fragments -> REGISTERS ----------------
    bf16x8 rbG[2][19];   // gates: per tile, 16 h-chunks + 3 w-chunks
    bf16x8 rbP[2][16];   // window: 2 n-tiles x 16 h-chunks
    #pragma unroll
    for (int tau = 0; tau < 2; ++tau) {
        const int colg = (lm >> 2) * 512 + blk * 8 + tau * 4 + (lm & 3);
        const float* wr = Whh + colg * 512;
        #pragma unroll
        for (int kc = 0; kc < 16; ++kc) {
            f32x4 lo = *(const f32x4*)(wr + kc * 32 + koff);
            f32x4 hi = *(const f32x4*)(wr + kc * 32 + koff + 4);
            bf16x8 b;
            b[0] = (__bf16)lo[0]; b[1] = (__bf16)lo[1];
            b[2] = (__bf16)lo[2]; b[3] = (__bf16)lo[3];
            b[4] = (__bf16)hi[0]; b[5] = (__bf16)hi[1];
            b[6] = (__bf16)hi[2]; b[7] = (__bf16)hi[3];
            rbG[tau][kc] = b;
        }
        #pragma unroll
        for (int kc = 0; kc < 3; ++kc) {
            bf16x8 b;
            #pragma unroll
            for (int j = 0; j < 8; ++j) {
                int k = kc * 32 + koff + j;
                b[j] = (__bf16)((k < 80) ? Wih[colg * 83 + 3 + k] : 0.f);
            }
            rbG[tau][16 + kc] = b;
        }
    }
    #pragma unroll
    for (int nt = 0; nt < 2; ++nt) {
        const int r = nt * 16 + lm;
        #pragma unroll
        for (int kc = 0; kc < 16; ++kc) {
            bf16x8 b;
            if (r < 30) {
                f32x4 lo = *(const f32x4*)(Wwin + r * 512 + kc * 32 + koff);
                f32x4 hi = *(const f32x4*)(Wwin + r * 512 + kc * 32 + koff + 4);
                b[0] = (__bf16)lo[0]; b[1] = (__bf16)lo[1];
                b[2] = (__bf16)lo[2]; b[3] = (__bf16)lo[3];
                b[4] = (__bf16)hi[0]; b[5] = (__bf16)hi[1];
                b[6] = (__bf16)hi[2]; b[7] = (__bf16)hi[3];
            } else {
                #pragma unroll
                for (int j = 0; j < 8; ++j) b[j] = (__bf16)0.f;
            }
            rbP[nt][kc] = b;
        }
    }

    // ---------------- one-time init: LDS ----------------
    for (int idx = tid; idx < 4096; idx += TPB) {
        S.Sent[idx]  = (unsigned char)sentences[idx];
        S.Maskv[idx] = smask[idx];
    }
    if (tid < 32) {
        int tau = tid >> 4, m = tid & 15;
        int colg = (m >> 2) * 512 + blk * 8 + tau * 4 + (m & 3);
        S.Bsum[tid] = bih[colg] + bhh[colg];
        S.Wx[tid * 3 + 0] = Wih[colg * 83 + 0];
        S.Wx[tid * 3 + 1] = Wih[colg * 83 + 1];
        S.Wx[tid * 3 + 2] = Wih[colg * 83 + 2];
        S.Bwin[tid] = (tid < 30) ? bwin[tid] : 0.f;
    }
    for (int idx = tid; idx < 640; idx += TPB) S.Ka[idx] = 0.f;
    for (int idx = tid; idx < 5120; idx += TPB) S.Wacc[idx] = 0.f;
    for (int idx = tid; idx < 64 * 104; idx += TPB) S.wBf[idx] = (__bf16)0.f;
    // per-wave x staging: lane<48 covers 16 batches x 3 features
    const float* xsrc = strokes + (wave * 16 + lane / 3) * 1536 + (lane % 3);
    if (lane < 48) S.Xt[wave * 48 + lane] = xsrc[0];   // x_0 -> buf 0
    float cst0 = 0.f, cst1 = 0.f;  // cell state: batch wave*16+(lane>>2), cols 2*(lane&3)+{0,1}
    __syncthreads();

    // per-lane loop-invariant constants (hoisted out of LDS)
    const float bs0 = S.Bsum[lm], bs1 = S.Bsum[16 + lm];
    const float bw0 = S.Bwin[lm], bw1 = S.Bwin[16 + lm];
    float wx[6];
    #pragma unroll
    for (int m = 0; m < 3; ++m) {
        wx[m]     = S.Wx[lm * 3 + m];
        wx[3 + m] = S.Wx[(16 + lm) * 3 + m];
    }
    const int pb  = wave * 16 + (lane >> 2);  // pointwise batch
    const int pa2 = lane & 3;                 // pointwise col pair
    bool waccDirty = false;

    // ---------------- main time loop ----------------
    for (int t = 0; t <= 512; ++t) {
        // phase 0+1 fused: poll OWN tagged data granules. granule g of batch row
        // = {u32 lo: 2 packed bf16 (h[2g],h[2g+1]), u32 hi: tag}. Want tag == t
        // (h_{t-1} was published with tag t; init-zero buffer == tag 0 == h_{-1}).
        const char* hb = (const char*)hbuf + (((t + 1) & 1) << 17) + myb * 2048 + quad * 32;
        f32x4 accG0, accG1, accP0, accP1;
        for (;;) {
            i32x4 L[32];
            #pragma unroll
            for (int kc = 0; kc < 16; ++kc) {
                L[2 * kc]     = *(const volatile i32x4*)(hb + kc * 128);
                L[2 * kc + 1] = *(const volatile i32x4*)(hb + kc * 128 + 16);
            }
            int bad = 0;
            #pragma unroll
            for (int kc = 0; kc < 32; ++kc)
                bad |= (L[kc].y ^ t) | (L[kc].w ^ t);
            if (__builtin_expect(__all(bad == 0), 1)) {
                accG0 = (f32x4){bs0, bs0, bs0, bs0};
                accG1 = (f32x4){bs1, bs1, bs1, bs1};
                accP0 = (f32x4){0.f, 0.f, 0.f, 0.f};
                accP1 = (f32x4){0.f, 0.f, 0.f, 0.f};
                #pragma unroll
                for (int kc = 0; kc < 16; ++kc) {
                    i32x4 fi = { L[2 * kc].x, L[2 * kc].z,
                                 L[2 * kc + 1].x, L[2 * kc + 1].z };
                    bf16x8 a = __builtin_bit_cast(bf16x8, fi);
                    accP0 = __builtin_amdgcn_mfma_f32_16x16x32_bf16(a, rbP[0][kc], accP0, 0, 0, 0);
                    accP1 = __builtin_amdgcn_mfma_f32_16x16x32_bf16(a, rbP[1][kc], accP1, 0, 0, 0);
                    accG0 = __builtin_amdgcn_mfma_f32_16x16x32_bf16(a, rbG[0][kc], accG0, 0, 0, 0);
                    accG1 = __builtin_amdgcn_mfma_f32_16x16x32_bf16(a, rbG[1][kc], accG1, 0, 0, 0);
                }
                break;
            }
        }

        // phase 2: scatter p (+b_win) -- rows are wave-local
        #pragma unroll
        for (int r = 0; r < 4; ++r) {
            int row = wave * 16 + quad * 4 + r;
            S.P[row * 33 + lm]      = accP0[r] + bw0;
            S.P[row * 33 + 16 + lm] = accP1[r] + bw1;
        }
        __builtin_amdgcn_wave_barrier();

        // phase 3: attention (wave-local, NO block barrier) -> w_{t-1}
        bool waveAny = false;
        if (t >= 1) {
            if (lane < 16) S.Act[wave * 16 + lane] = 0;
            __builtin_amdgcn_wave_barrier();
            #pragma unroll
            for (int it = 0; it < 3; ++it) {
                int idx = lane + it * 64;
                if (idx < 160) {
                    int bl = idx / 10, k = idx - bl * 10;
                    int gb = wave * 16 + bl, ad = gb * 10 + k;
                    float ka = S.Ka[ad] + __expf(S.P[gb * 33 + 20 + k]);
                    S.Ka[ad] = ka;
                    S.Al[ad] = __expf(S.P[gb * 33 + k]);
                    float be = __expf(S.P[gb * 33 + 10 + k]);
                    S.Be[ad] = be;
                    float dmin = fmaxf(fmaxf(-ka, ka - 63.f), 0.f);
                    if (be * dmin * dmin <= 36.f) atomicOr(&S.Act[gb], 1);
                }
            }
            __builtin_amdgcn_wave_barrier();
            int actv = (lane < 16) ? S.Act[wave * 16 + lane] : 0;
            waveAny = __any(actv != 0);
            if (waccDirty) {
                for (int i = lane; i < 1280; i += 64) S.Wacc[wave * 1280 + i] = 0.f;
            }
            __builtin_amdgcn_wave_barrier();
            if (waveAny) {
                #pragma unroll 1
                for (int ii = 0; ii < 16; ++ii) {
                    int gb = wave * 16 + ii;
                    if (!S.Act[gb]) continue;   // wave-uniform
                    float uu = (float)lane;
                    float s = 0.f;
                    #pragma unroll
                    for (int k = 0; k < 10; ++k) {
                        float d = S.Ka[gb * 10 + k] - uu;
                        s = fmaf(S.Al[gb * 10 + k], __expf(-S.Be[gb * 10 + k] * d * d), s);
                    }
                    float val = s * S.Maskv[gb * 64 + lane];
                    if (val != 0.f)
                        atomicAdd(&S.Wacc[gb * 80 + (int)S.Sent[gb * 64 + lane]], val);
                }
            }
            __builtin_amdgcn_wave_barrier();
            if (waveAny || waccDirty) {
                for (int i = lane; i < 1280; i += 64) {
                    int bl = i / 80, n = i - bl * 80;
                    S.wBf[(wave * 16 + bl) * 104 + n] = (__bf16)S.Wacc[wave * 1280 + i];
                }
            }
            __builtin_amdgcn_wave_barrier();
        }

        float hv0 = 0.f, hv1 = 0.f;
        if (t < 512) {
            // phase 4: w-part of gates (skip when wBf is all-zero)
            if (waveAny) {
                const __bf16* wrow = S.wBf + myb * 104 + koff;
                #pragma unroll
                for (int kc = 0; kc < 3; ++kc) {
                    bf16x8 a = *(const bf16x8*)(wrow + kc * 32);
                    accG0 = __builtin_amdgcn_mfma_f32_16x16x32_bf16(a, rbG[0][16 + kc], accG0, 0, 0, 0);
                    accG1 = __builtin_amdgcn_mfma_f32_16x16x32_bf16(a, rbG[1][16 + kc], accG1, 0, 0, 0);
                }
            }
            // phase 5: add x-part, scatter gates (wave-local rows)
            const float* xb = &S.Xt[(t & 1) * 192 + wave * 48];
            #pragma unroll
            for (int r = 0; r < 4; ++r) {
                int row = wave * 16 + quad * 4 + r;
                float x0 = xb[(quad * 4 + r) * 3 + 0];
                float x1 = xb[(quad * 4 + r) * 3 + 1];
                float x2 = xb[(quad * 4 + r) * 3 + 2];
                S.Gt[row * 33 + lm]      = accG0[r] + x0 * wx[0] + x1 * wx[1] + x2 * wx[2];
                S.Gt[row * 33 + 16 + lm] = accG1[r] + x0 * wx[3] + x1 * wx[4] + x2 * wx[5];
            }
            __builtin_amdgcn_wave_barrier();
            // phase 6: LSTM pointwise (reads wave-local Gt rows), publish h_t
            {
                const float* g = &S.Gt[pb * 33];
                {
                    int c = 2 * pa2, tau = c >> 2, mm = c & 3;
                    const float* gg = g + tau * 16;
                    float cc = sigf(gg[4 + mm]) * cst0 + sigf(gg[mm]) * tanh_fast(gg[8 + mm]);
                    cst0 = cc;
                    hv0 = sigf(gg[12 + mm]) * tanh_fast(cc);
                }
                {
                    int c = 2 * pa2 + 1, tau = c >> 2, mm = c & 3;
                    const float* gg = g + tau * 16;
                    float cc = sigf(gg[4 + mm]) * cst1 + sigf(gg[mm]) * tanh_fast(gg[8 + mm]);
                    cst1 = cc;
                    hv1 = sigf(gg[12 + mm]) * tanh_fast(cc);
                }
                union { __bf16 q[2]; unsigned u; } pk;
                pk.q[0] = (__bf16)hv0; pk.q[1] = (__bf16)hv1;
                // tagged atomic 8B publish: {data, tag=t+1}. Fire-and-forget --
                // no drain, no flag. Consumers validate via the tag.
                unsigned long long pv =
                    ((unsigned long long)(unsigned)(t + 1) << 32) | (unsigned long long)pk.u;
                ((volatile unsigned long long*)hbuf)[(t & 1) * 16384 + pb * 256 + blk * 4 + pa2] = pv;
            }
            // outputs + per-wave x prefetch -- off the critical path
            {
                f32x2 ho = {hv0, hv1};
                *(f32x2*)(out + pb * 262144 + t * 512 + blk * 8 + 2 * pa2) = ho;
            }
            if (t + 1 < 512 && lane < 48)
                S.Xt[((t + 1) & 1) * 192 + wave * 48 + lane] = xsrc[(t + 1) * 3];
        }
        waccDirty = waveAny;

        if (t >= 1 && wave == (blk >> 4)) {
            // this block stores ws for batch blk (owned by this wave)
            for (int n = lane; n < 80; n += 64)
                out[16777216 + blk * 40960 + (t - 1) * 80 + n] = S.Wacc[blk * 80 + n];
        }
    }
}

extern "C" void kernel_launch(void* const* d_in, const int* in_sizes, int n_in,
                              void* d_out, int out_size, void* d_ws, size_t ws_size,
                              hipStream_t stream) {
    const float* strokes   = (const float*)d_in[0];
    const int*   sentences = (const int*)d_in[1];
    const float* smask     = (const float*)d_in[2];
    const float* Wih       = (const float*)d_in[3];
    const float* Whh       = (const float*)d_in[4];
    const float* bih       = (const float*)d_in[5];
    const float* bhh       = (const float*)d_in[6];
    const float* Wwin      = (const float*)d_in[7];
    const float* bwin      = (const float*)d_in[8];
    float* out = (float*)d_out;
    unsigned long long* hbuf = (unsigned long long*)d_ws;

    init_ws_kernel<<<256, TPB, 0, stream>>>((int*)d_ws);
    lstm_attn<<<GRID_BLOCKS, TPB, 0, stream>>>(strokes, sentences, smask, Wih, Whh,
                                               bih, bhh, Wwin, bwin, out, hbuf);
}

// Round 3
// 3402.164 us; speedup vs baseline: 2.4108x; 2.4108x over previous
//
#include <hip/hip_runtime.h>
#include <hip/hip_bf16.h>

// LSTM + Gaussian attention (Graves), B=64, T=512, H=512, K=10, NC=80, U=64.
// 64 persistent blocks x 256 threads, each block owns 8 h-cols (32 gate cols).
// Wave w of each block owns batches [16w,16w+16) for ALL intra-step phases.
// Cross-block h broadcast: MALL-coherent sc0/sc1; 16 h loads batched in one
// asm block (single round trip).
// R8 sync: PER-WAVE RINGS. flags[wave][block]; each wave's 64 lanes poll the
// 64 peer-block flags of ITS ring only (one coalesced 256B load/iter), then
// proceeds independently -- NO __syncthreads in the main loop, no wave0 proxy.
// Ring w's attention work is identical across blocks, so within-ring skew is
// minimal; rings decouple from each other. x_t staging is per-wave.

#define GRID_BLOCKS 64
#define TPB 256

typedef __attribute__((ext_vector_type(8))) __bf16 bf16x8;
typedef __attribute__((ext_vector_type(4))) float f32x4;
typedef __attribute__((ext_vector_type(2))) float f32x2;

struct Smem {
    alignas(16) __bf16 wBf[64 * 104];  // w (attention) bf16, padded stride 104
    float P[64 * 33];                  // window pre-acts (30 cols), stride 33
    float Gt[64 * 33];                 // gates scatter (32 cols), stride 33
    float Al[640];
    float Be[640];
    float Ka[640];                     // kappa (replicated per block)
    float Wacc[64 * 80];               // w accumulator fp32
    float Xt[2 * 192];                 // x_t staged, per-wave [buf][wave][48]
    float Maskv[4096];
    float Wx[96];                      // x-part weights, 32 cols x 3
    float Bsum[32];
    float Bwin[32];
    int   Act[64];
    unsigned char Sent[4096];
};

__device__ __forceinline__ float sigf(float x) {
    return 1.f / (1.f + __expf(-x));
}
__device__ __forceinline__ float tanh_fast(float x) {
    float xx = fminf(fmaxf(x, -15.f), 15.f);
    float e = __expf(2.f * xx);
    return (e - 1.f) / (e + 1.f);
}

__global__ void init_ws_kernel(int* ws) {
    // zero h double-buffer (131072 B) + 4 rings x 64 flags (1024 B)
    int idx = blockIdx.x * TPB + threadIdx.x;
    if (idx < 33792) ws[idx] = 0;
}

__global__ void __launch_bounds__(TPB, 1) lstm_attn(
    const float* __restrict__ strokes,    // [64][512][3]
    const int*   __restrict__ sentences,  // [64][64]
    const float* __restrict__ smask,      // [64][64]
    const float* __restrict__ Wih,        // [2048][83]
    const float* __restrict__ Whh,        // [2048][512]
    const float* __restrict__ bih,        // [2048]
    const float* __restrict__ bhh,        // [2048]
    const float* __restrict__ Wwin,      // [30][512]
    const float* __restrict__ bwin,      // [30]
    float* __restrict__ out,             // hs [64][512][512] ++ ws [64][512][80]
    unsigned short* __restrict__ hbuf,   // [2][64][512] bf16 bits (MALL-coherent)
    int* __restrict__ flags)             // [4 rings][64 blocks]
{
    __shared__ Smem S;
    const int tid  = threadIdx.x;
    const int blk  = blockIdx.x;
    const int lane = tid & 63;
    const int wave = tid >> 6;
    const int lm   = lane & 15;   // MFMA n-col within tile / A row
    const int quad = lane >> 4;   // MFMA k-block
    const int myb  = wave * 16 + lm;
    const int koff = quad * 8;

    // ---------------- one-time init: B-fragments -> REGISTERS ----------------
    bf16x8 rbG[2][19];   // gates: per tile, 16 h-chunks + 3 w-chunks
    bf16x8 rbP[2][16];   // window: 2 n-tiles x 16 h-chunks
    #pragma unroll
    for (int tau = 0; tau < 2; ++tau) {
        const int colg = (lm >> 2) * 512 + blk * 8 + tau * 4 + (lm & 3);
        const float* wr = Whh + colg * 512;
        #pragma unroll
        for (int kc = 0; kc < 16; ++kc) {
            f32x4 lo = *(const f32x4*)(wr + kc * 32 + koff);
            f32x4 hi = *(const f32x4*)(wr + kc * 32 + koff + 4);
            bf16x8 b;
            b[0] = (__bf16)lo[0]; b[1] = (__bf16)lo[1];
            b[2] = (__bf16)lo[2]; b[3] = (__bf16)lo[3];
            b[4] = (__bf16)hi[0]; b[5] = (__bf16)hi[1];
            b[6] = (__bf16)hi[2]; b[7] = (__bf16)hi[3];
            rbG[tau][kc] = b;
        }
        #pragma unroll
        for (int kc = 0; kc < 3; ++kc) {
            bf16x8 b;
            #pragma unroll
            for (int j = 0; j < 8; ++j) {
                int k = kc * 32 + koff + j;
                b[j] = (__bf16)((k < 80) ? Wih[colg * 83 + 3 + k] : 0.f);
            }
            rbG[tau][16 + kc] = b;
        }
    }
    #pragma unroll
    for (int nt = 0; nt < 2; ++nt) {
        const int r = nt * 16 + lm;
        #pragma unroll
        for (int kc = 0; kc < 16; ++kc) {
            bf16x8 b;
            if (r < 30) {
                f32x4 lo = *(const f32x4*)(Wwin + r * 512 + kc * 32 + koff);
                f32x4 hi = *(const f32x4*)(Wwin + r * 512 + kc * 32 + koff + 4);
                b[0] = (__bf16)lo[0]; b[1] = (__bf16)lo[1];
                b[2] = (__bf16)lo[2]; b[3] = (__bf16)lo[3];
                b[4] = (__bf16)hi[0]; b[5] = (__bf16)hi[1];
                b[6] = (__bf16)hi[2]; b[7] = (__bf16)hi[3];
            } else {
                #pragma unroll
                for (int j = 0; j < 8; ++j) b[j] = (__bf16)0.f;
            }
            rbP[nt][kc] = b;
        }
    }

    // ---------------- one-time init: LDS ----------------
    for (int idx = tid; idx < 4096; idx += TPB) {
        S.Sent[idx]  = (unsigned char)sentences[idx];
        S.Maskv[idx] = smask[idx];
    }
    if (tid < 32) {
        int tau = tid >> 4, m = tid & 15;
        int colg = (m >> 2) * 512 + blk * 8 + tau * 4 + (m & 3);
        S.Bsum[tid] = bih[colg] + bhh[colg];
        S.Wx[tid * 3 + 0] = Wih[colg * 83 + 0];
        S.Wx[tid * 3 + 1] = Wih[colg * 83 + 1];
        S.Wx[tid * 3 + 2] = Wih[colg * 83 + 2];
        S.Bwin[tid] = (tid < 30) ? bwin[tid] : 0.f;
    }
    for (int idx = tid; idx < 640; idx += TPB) S.Ka[idx] = 0.f;
    for (int idx = tid; idx < 5120; idx += TPB) S.Wacc[idx] = 0.f;
    for (int idx = tid; idx < 64 * 104; idx += TPB) S.wBf[idx] = (__bf16)0.f;
    // per-wave x staging: lane<48 covers this wave's 16 batches x 3 features
    const float* xsrc = strokes + (wave * 16 + lane / 3) * 1536 + (lane % 3);
    if (lane < 48) S.Xt[wave * 48 + lane] = xsrc[0];   // x_0 -> buf 0
    float cst0 = 0.f, cst1 = 0.f;  // cell state: batch wave*16+(lane>>2), cols 2*(lane&3)+{0,1}
    __syncthreads();

    // per-lane loop-invariant constants (hoisted out of LDS)
    const float bs0 = S.Bsum[lm], bs1 = S.Bsum[16 + lm];
    const float bw0 = S.Bwin[lm], bw1 = S.Bwin[16 + lm];
    float wx[6];
    #pragma unroll
    for (int m = 0; m < 3; ++m) {
        wx[m]     = S.Wx[lm * 3 + m];
        wx[3 + m] = S.Wx[(16 + lm) * 3 + m];
    }
    const int pb  = wave * 16 + (lane >> 2);  // pointwise batch
    const int pa2 = lane & 3;                 // pointwise col pair
    bool waccDirty = false;
    // ring poll/publish addresses
    const volatile int* pollAddr = (const volatile int*)flags + wave * 64 + lane;
    volatile int* pubAddr = (volatile int*)flags + wave * 64 + blk;

    // ---------------- main time loop ----------------
    for (int t = 0; t <= 512; ++t) {
        // phase 0: each wave polls ITS ring's 64 peer flags (coalesced 256B)
        if (t >= 1) {
            for (;;) {
                int v = *pollAddr;
                if (__all(v >= t)) break;
                __builtin_amdgcn_s_sleep(1);
            }
        }
        // phase 1: batched MALL-coherent h loads -- ONE round trip
        const unsigned short* hb = hbuf + ((t + 1) & 1) * 32768 + myb * 512 + koff;
        f32x4 h0,h1,h2,h3,h4,h5,h6,h7,h8,h9,h10,h11,h12,h13,h14,h15;
        asm volatile(
            "global_load_dwordx4 %0, %16, off sc0 sc1\n\t"
            "global_load_dwordx4 %1, %16, off offset:64 sc0 sc1\n\t"
            "global_load_dwordx4 %2, %16, off offset:128 sc0 sc1\n\t"
            "global_load_dwordx4 %3, %16, off offset:192 sc0 sc1\n\t"
            "global_load_dwordx4 %4, %16, off offset:256 sc0 sc1\n\t"
            "global_load_dwordx4 %5, %16, off offset:320 sc0 sc1\n\t"
            "global_load_dwordx4 %6, %16, off offset:384 sc0 sc1\n\t"
            "global_load_dwordx4 %7, %16, off offset:448 sc0 sc1\n\t"
            "global_load_dwordx4 %8, %16, off offset:512 sc0 sc1\n\t"
            "global_load_dwordx4 %9, %16, off offset:576 sc0 sc1\n\t"
            "global_load_dwordx4 %10, %16, off offset:640 sc0 sc1\n\t"
            "global_load_dwordx4 %11, %16, off offset:704 sc0 sc1\n\t"
            "global_load_dwordx4 %12, %16, off offset:768 sc0 sc1\n\t"
            "global_load_dwordx4 %13, %16, off offset:832 sc0 sc1\n\t"
            "global_load_dwordx4 %14, %16, off offset:896 sc0 sc1\n\t"
            "global_load_dwordx4 %15, %16, off offset:960 sc0 sc1\n\t"
            "s_waitcnt vmcnt(0)"
            : "=&v"(h0), "=&v"(h1), "=&v"(h2), "=&v"(h3),
              "=&v"(h4), "=&v"(h5), "=&v"(h6), "=&v"(h7),
              "=&v"(h8), "=&v"(h9), "=&v"(h10), "=&v"(h11),
              "=&v"(h12), "=&v"(h13), "=&v"(h14), "=&v"(h15)
            : "v"(hb)
            : "memory");

        // MFMAs: window first (feeds the long attention chain), then gates
        f32x4 accG0 = {bs0, bs0, bs0, bs0};
        f32x4 accG1 = {bs1, bs1, bs1, bs1};
        f32x4 accP0 = {0.f, 0.f, 0.f, 0.f};
        f32x4 accP1 = {0.f, 0.f, 0.f, 0.f};
        #define KSTEP(R, I) { bf16x8 a = __builtin_bit_cast(bf16x8, R); \
            accP0 = __builtin_amdgcn_mfma_f32_16x16x32_bf16(a, rbP[0][I], accP0, 0, 0, 0); \
            accP1 = __builtin_amdgcn_mfma_f32_16x16x32_bf16(a, rbP[1][I], accP1, 0, 0, 0); \
            accG0 = __builtin_amdgcn_mfma_f32_16x16x32_bf16(a, rbG[0][I], accG0, 0, 0, 0); \
            accG1 = __builtin_amdgcn_mfma_f32_16x16x32_bf16(a, rbG[1][I], accG1, 0, 0, 0); }
        KSTEP(h0, 0)  KSTEP(h1, 1)  KSTEP(h2, 2)  KSTEP(h3, 3)
        KSTEP(h4, 4)  KSTEP(h5, 5)  KSTEP(h6, 6)  KSTEP(h7, 7)
        KSTEP(h8, 8)  KSTEP(h9, 9)  KSTEP(h10, 10) KSTEP(h11, 11)
        KSTEP(h12, 12) KSTEP(h13, 13) KSTEP(h14, 14) KSTEP(h15, 15)
        #undef KSTEP

        // phase 2: scatter p (+b_win) -- rows are wave-local
        #pragma unroll
        for (int r = 0; r < 4; ++r) {
            int row = wave * 16 + quad * 4 + r;
            S.P[row * 33 + lm]      = accP0[r] + bw0;
            S.P[row * 33 + 16 + lm] = accP1[r] + bw1;
        }
        __builtin_amdgcn_wave_barrier();

        // phase 3: attention (wave-local, NO block barrier) -> w_{t-1}
        bool waveAny = false;
        if (t >= 1) {
            if (lane < 16) S.Act[wave * 16 + lane] = 0;
            __builtin_amdgcn_wave_barrier();
            #pragma unroll
            for (int it = 0; it < 3; ++it) {
                int idx = lane + it * 64;
                if (idx < 160) {
                    int bl = idx / 10, k = idx - bl * 10;
                    int gb = wave * 16 + bl, ad = gb * 10 + k;
                    float ka = S.Ka[ad] + __expf(S.P[gb * 33 + 20 + k]);
                    S.Ka[ad] = ka;
                    S.Al[ad] = __expf(S.P[gb * 33 + k]);
                    float be = __expf(S.P[gb * 33 + 10 + k]);
                    S.Be[ad] = be;
                    float dmin = fmaxf(fmaxf(-ka, ka - 63.f), 0.f);
                    if (be * dmin * dmin <= 36.f) atomicOr(&S.Act[gb], 1);
                }
            }
            __builtin_amdgcn_wave_barrier();
            int actv = (lane < 16) ? S.Act[wave * 16 + lane] : 0;
            waveAny = __any(actv != 0);
            if (waccDirty) {
                for (int i = lane; i < 1280; i += 64) S.Wacc[wave * 1280 + i] = 0.f;
            }
            __builtin_amdgcn_wave_barrier();
            if (waveAny) {
                #pragma unroll 1
                for (int ii = 0; ii < 16; ++ii) {
                    int gb = wave * 16 + ii;
                    if (!S.Act[gb]) continue;   // wave-uniform
                    float uu = (float)lane;
                    float s = 0.f;
                    #pragma unroll
                    for (int k = 0; k < 10; ++k) {
                        float d = S.Ka[gb * 10 + k] - uu;
                        s = fmaf(S.Al[gb * 10 + k], __expf(-S.Be[gb * 10 + k] * d * d), s);
                    }
                    float val = s * S.Maskv[gb * 64 + lane];
                    if (val != 0.f)
                        atomicAdd(&S.Wacc[gb * 80 + (int)S.Sent[gb * 64 + lane]], val);
                }
            }
            __builtin_amdgcn_wave_barrier();
            if (waveAny || waccDirty) {
                for (int i = lane; i < 1280; i += 64) {
                    int bl = i / 80, n = i - bl * 80;
                    S.wBf[(wave * 16 + bl) * 104 + n] = (__bf16)S.Wacc[wave * 1280 + i];
                }
            }
            __builtin_amdgcn_wave_barrier();
        }

        float hv0 = 0.f, hv1 = 0.f;
        if (t < 512) {
            // phase 4: w-part of gates (skip when wBf is all-zero)
            if (waveAny) {
                const __bf16* wrow = S.wBf + myb * 104 + koff;
                #pragma unroll
                for (int kc = 0; kc < 3; ++kc) {
                    bf16x8 a = *(const bf16x8*)(wrow + kc * 32);
                    accG0 = __builtin_amdgcn_mfma_f32_16x16x32_bf16(a, rbG[0][16 + kc], accG0, 0, 0, 0);
                    accG1 = __builtin_amdgcn_mfma_f32_16x16x32_bf16(a, rbG[1][16 + kc], accG1, 0, 0, 0);
                }
            }
            // phase 5: add x-part, scatter gates (wave-local rows)
            const float* xb = &S.Xt[(t & 1) * 192 + wave * 48];
            #pragma unroll
            for (int r = 0; r < 4; ++r) {
                int row = wave * 16 + quad * 4 + r;
                float x0 = xb[(quad * 4 + r) * 3 + 0];
                float x1 = xb[(quad * 4 + r) * 3 + 1];
                float x2 = xb[(quad * 4 + r) * 3 + 2];
                S.Gt[row * 33 + lm]      = accG0[r] + x0 * wx[0] + x1 * wx[1] + x2 * wx[2];
                S.Gt[row * 33 + 16 + lm] = accG1[r] + x0 * wx[3] + x1 * wx[4] + x2 * wx[5];
            }
            __builtin_amdgcn_wave_barrier();
            // phase 6: LSTM pointwise (reads wave-local Gt rows), publish h_t
            {
                const float* g = &S.Gt[pb * 33];
                {
                    int c = 2 * pa2, tau = c >> 2, mm = c & 3;
                    const float* gg = g + tau * 16;
                    float cc = sigf(gg[4 + mm]) * cst0 + sigf(gg[mm]) * tanh_fast(gg[8 + mm]);
                    cst0 = cc;
                    hv0 = sigf(gg[12 + mm]) * tanh_fast(cc);
                }
                {
                    int c = 2 * pa2 + 1, tau = c >> 2, mm = c & 3;
                    const float* gg = g + tau * 16;
                    float cc = sigf(gg[4 + mm]) * cst1 + sigf(gg[mm]) * tanh_fast(gg[8 + mm]);
                    cst1 = cc;
                    hv1 = sigf(gg[12 + mm]) * tanh_fast(cc);
                }
                union { __bf16 q[2]; unsigned u; } pk;
                pk.q[0] = (__bf16)hv0; pk.q[1] = (__bf16)hv1;
                ((volatile unsigned*)hbuf)[(t & 1) * 16384 + pb * 256 + blk * 4 + pa2] = pk.u;
            }
            // producer release (PER WAVE): drain own h stores, publish ring flag
            asm volatile("s_waitcnt vmcnt(0)" ::: "memory");
            if (lane == 0) *pubAddr = t + 1;
            // outputs + per-wave x prefetch AFTER the publish -- off the critical path
            {
                f32x2 ho = {hv0, hv1};
                *(f32x2*)(out + pb * 262144 + t * 512 + blk * 8 + 2 * pa2) = ho;
            }
            if (t + 1 < 512 && lane < 48)
                S.Xt[((t + 1) & 1) * 192 + wave * 48 + lane] = xsrc[(t + 1) * 3];
        }
        waccDirty = waveAny;

        if (t >= 1 && wave == (blk >> 4)) {
            // this block stores ws for batch blk (owned by this wave)
            for (int n = lane; n < 80; n += 64)
                out[16777216 + blk * 40960 + (t - 1) * 80 + n] = S.Wacc[blk * 80 + n];
        }
    }
}

extern "C" void kernel_launch(void* const* d_in, const int* in_sizes, int n_in,
                              void* d_out, int out_size, void* d_ws, size_t ws_size,
                              hipStream_t stream) {
    const float* strokes   = (const float*)d_in[0];
    const int*   sentences = (const int*)d_in[1];
    const float* smask     = (const float*)d_in[2];
    const float* Wih       = (const float*)d_in[3];
    const float* Whh       = (const float*)d_in[4];
    const float* bih       = (const float*)d_in[5];
    const float* bhh       = (const float*)d_in[6];
    const float* Wwin      = (const float*)d_in[7];
    const float* bwin      = (const float*)d_in[8];
    float* out = (float*)d_out;
    unsigned short* hbuf = (unsigned short*)d_ws;
    int* flags = (int*)((char*)d_ws + 131072);

    init_ws_kernel<<<132, TPB, 0, stream>>>((int*)d_ws);
    lstm_attn<<<GRID_BLOCKS, TPB, 0, stream>>>(strokes, sentences, smask, Wih, Whh,
                                               bih, bhh, Wwin, bwin, out, hbuf, flags);
}